// Round 1
// baseline (295.909 us; speedup 1.0000x reference)
//
#include <hip/hip_runtime.h>
#include <hip/hip_bf16.h>
#include <math.h>

#define GG 8192      // graphs = B*T
#define NODESN 23
#define KK 8
#define DIN 16
#define HH 128
#define RHH 128
#define EPG (NODESN*KK)   // 184 edges per graph
#define TTT 128
#define BBB 64

// ---------------------------------------------------------------------------
// Kernel 1: fully fused 2-layer GCN, one block per graph.
// Exploits: deg == 9 for every node (deterministic dst pattern), so norm = 1/9.
// Only the runner node's layer-2 output is needed:
//   h2[runner] = relu( (1/9) * (hsum @ W2) + b2 ),  hsum = sum of 9 relu'd h1 rows
// ---------------------------------------------------------------------------
__global__ __launch_bounds__(256) void gcn_fused(
    const float* __restrict__ x, const int* __restrict__ esrc,
    const int* __restrict__ runner,
    const float* __restrict__ W1, const float* __restrict__ b1,
    const float* __restrict__ W2, const float* __restrict__ b2,
    float* __restrict__ seq)
{
    __shared__ float xs[NODESN * DIN];     // 23*16
    __shared__ float W1s[DIN * HH];        // 16*128
    __shared__ int   srcs[EPG];            // 184 local src indices
    __shared__ float t1[NODESN * HH];      // 23*128  (x @ W1)
    __shared__ float b1s[HH];
    __shared__ float hsum[HH];
    __shared__ float red[256];

    const int g = blockIdx.x;
    const int tid = threadIdx.x;

    // ---- stage inputs ----
    for (int i = tid; i < NODESN * DIN; i += 256) xs[i] = x[g * NODESN * DIN + i];
    for (int i = tid; i < DIN * HH; i += 256)     W1s[i] = W1[i];
    for (int i = tid; i < EPG; i += 256)          srcs[i] = esrc[g * EPG + i] - g * NODESN;
    if (tid < HH) b1s[tid] = b1[tid];
    __syncthreads();

    // ---- t1 = x @ W1  (23x16 @ 16x128) ----
    for (int idx = tid; idx < NODESN * HH; idx += 256) {
        int n = idx >> 7, j = idx & 127;
        float acc = 0.f;
        #pragma unroll
        for (int k = 0; k < DIN; k += 4) {
            float4 xv = *(const float4*)&xs[n * DIN + k];
            acc = fmaf(xv.x, W1s[(k+0)*HH + j],
                  fmaf(xv.y, W1s[(k+1)*HH + j],
                  fmaf(xv.z, W1s[(k+2)*HH + j],
                  fmaf(xv.w, W1s[(k+3)*HH + j], acc))));
        }
        t1[idx] = acc;
    }
    __syncthreads();

    // ---- hsum = sum over 9 slots (runner + its 8 srcs) of relu'd h1 rows ----
    // h1[node] = relu( (1/9)*(t1[node] + sum_k t1[srcs(node,k)]) + b1 )
    const int r = runner[g];
    {
        const int j = tid & 127, sgrp = tid >> 7;   // 2 slot groups
        float part = 0.f;
        for (int slot = sgrp; slot < 9; slot += 2) {
            int node = (slot < 8) ? srcs[r * KK + slot] : r;
            float acc = t1[node * HH + j];
            #pragma unroll
            for (int k = 0; k < KK; k++) acc += t1[srcs[node * KK + k] * HH + j];
            part += fmaxf(acc * (1.f / 9.f) + b1s[j], 0.f);
        }
        red[tid] = part;
    }
    __syncthreads();
    if (tid < HH) hsum[tid] = red[tid] + red[tid + 128];
    __syncthreads();

    // ---- h2_runner = relu( (1/9)*(hsum @ W2) + b2 ) ; write to seq[g] ----
    {
        const int j = tid & 127, kh = tid >> 7;  // 2-way k split
        float acc = 0.f;
        #pragma unroll
        for (int kq = 0; kq < 16; kq++) {
            int k = kh * 64 + kq * 4;
            float4 hv = *(const float4*)&hsum[k];
            acc = fmaf(hv.x, W2[(k+0)*HH + j],
                  fmaf(hv.y, W2[(k+1)*HH + j],
                  fmaf(hv.z, W2[(k+2)*HH + j],
                  fmaf(hv.w, W2[(k+3)*HH + j], acc))));
        }
        red[tid] = acc;
    }
    __syncthreads();
    if (tid < HH)
        seq[(size_t)g * HH + tid] =
            fmaxf((red[tid] + red[tid + 128]) * (1.f / 9.f) + b2[tid], 0.f);
}

// ---------------------------------------------------------------------------
// Kernel 2: transpose W_ih [384,128] -> WT [128,384] for coalesced access
// ---------------------------------------------------------------------------
__global__ void transpose_wih(const float* __restrict__ W, float* __restrict__ WT)
{
    int idx = blockIdx.x * 256 + threadIdx.x;
    if (idx < 3 * RHH * RHH) {
        int jj = idx / RHH, kk = idx - jj * RHH;
        WT[kk * (3 * RHH) + jj] = W[idx];
    }
}

// ---------------------------------------------------------------------------
// Kernel 3: xg = seq @ W_ih^T + b_ih   [8192,128]@[128,384]
// 8 rows per block; seq row addresses are wave-uniform -> scalar loads
// ---------------------------------------------------------------------------
__global__ __launch_bounds__(384) void xg_kernel(
    const float* __restrict__ seq, const float* __restrict__ WT,
    const float* __restrict__ b_ih, float* __restrict__ xg)
{
    const int tid = threadIdx.x;              // j in [0,384)
    const int m0 = blockIdx.x * 8;
    const float* srow = seq + (size_t)m0 * RHH;
    float acc[8];
    const float bv = b_ih[tid];
    #pragma unroll
    for (int mi = 0; mi < 8; mi++) acc[mi] = bv;
    for (int k = 0; k < RHH; k += 4) {
        float w0 = WT[(k+0)*384 + tid];
        float w1 = WT[(k+1)*384 + tid];
        float w2 = WT[(k+2)*384 + tid];
        float w3 = WT[(k+3)*384 + tid];
        #pragma unroll
        for (int mi = 0; mi < 8; mi++) {
            float4 sv = *(const float4*)(srow + mi * RHH + k);
            acc[mi] = fmaf(sv.x, w0, fmaf(sv.y, w1, fmaf(sv.z, w2, fmaf(sv.w, w3, acc[mi]))));
        }
    }
    #pragma unroll
    for (int mi = 0; mi < 8; mi++)
        xg[(size_t)(m0 + mi) * 384 + tid] = acc[mi];
}

// ---------------------------------------------------------------------------
// Kernel 4: GRU (sequential over T) + fused output projection.
// One block per batch element (64 blocks, 768 threads = 12 waves).
// Thread (j, half) holds 64 W_hh weights in VGPRs; h history kept in LDS so
// the final projection out = outs @ Wp + bp is done in-block at the end.
// ---------------------------------------------------------------------------
__global__ __launch_bounds__(768) void gru_kernel(
    const float* __restrict__ xg, const float* __restrict__ W_hh,
    const float* __restrict__ b_hh, const float* __restrict__ Wp,
    const float* __restrict__ bp, float* __restrict__ out)
{
    __shared__ float h_hist[(TTT + 1) * RHH];   // 129*128 floats = 66 KB
    __shared__ float gh_s[3 * RHH];
    __shared__ float part_s[3 * RHH];

    const int b = blockIdx.x;
    const int tid = threadIdx.x;
    const int half = tid / 384;          // waves 0-5: half 0, waves 6-11: half 1
    const int j = tid - half * 384;      // gate-output index [0,384)

    // preload W_hh[j][half*64 .. half*64+63] into registers
    float w[64];
    const float* wrow = W_hh + (size_t)j * RHH + half * 64;
    #pragma unroll
    for (int q = 0; q < 16; q++) {
        float4 wv = *(const float4*)(wrow + 4 * q);
        w[4*q+0] = wv.x; w[4*q+1] = wv.y; w[4*q+2] = wv.z; w[4*q+3] = wv.w;
    }
    const float bhh = b_hh[j];

    if (tid < RHH) h_hist[tid] = 0.f;    // h0 = 0
    __syncthreads();

    const float* xrow = xg + (size_t)b * TTT * 3 * RHH;

    for (int t = 0; t < TTT; t++) {
        // gh[j] = h_prev . W_hh[j,:]  (2-way k split)
        const float* hs = &h_hist[t * RHH + half * 64];
        float acc = 0.f;
        #pragma unroll
        for (int q = 0; q < 16; q++) {
            float4 hv = *(const float4*)(hs + 4 * q);
            acc = fmaf(hv.x, w[4*q+0],
                  fmaf(hv.y, w[4*q+1],
                  fmaf(hv.z, w[4*q+2],
                  fmaf(hv.w, w[4*q+3], acc))));
        }
        if (half) part_s[j] = acc;
        __syncthreads();
        if (!half) gh_s[j] = acc + part_s[j] + bhh;
        __syncthreads();

        if (tid < RHH) {
            const int i = tid;
            float xr = xrow[t * 384 + i];
            float xz = xrow[t * 384 + RHH + i];
            float xn = xrow[t * 384 + 2 * RHH + i];
            float hr = gh_s[i], hz = gh_s[RHH + i], hn = gh_s[2 * RHH + i];
            float rg = 1.f / (1.f + expf(-(xr + hr)));
            float zg = 1.f / (1.f + expf(-(xz + hz)));
            float ng = tanhf(fmaf(rg, hn, xn));
            float hnew = fmaf(zg, h_hist[t * RHH + i], (1.f - zg) * ng);
            h_hist[(t + 1) * RHH + i] = hnew;
        }
        __syncthreads();
    }

    // fused projection: out[b,t,:] = h_hist[t+1] @ Wp + bp
    for (int idx = tid; idx < TTT * 2; idx += 768) {
        int t = idx >> 1, c = idx & 1;
        float acc = bp[c];
        for (int i = 0; i < RHH; i++)
            acc = fmaf(h_hist[(t + 1) * RHH + i], Wp[i * 2 + c], acc);
        out[((size_t)b * TTT + t) * 2 + c] = acc;
    }
}

extern "C" void kernel_launch(void* const* d_in, const int* in_sizes, int n_in,
                              void* d_out, int out_size, void* d_ws, size_t ws_size,
                              hipStream_t stream)
{
    const float* x      = (const float*)d_in[0];
    const int*   eidx   = (const int*)d_in[1];   // [2, E]; row 0 = src
    const int*   runner = (const int*)d_in[2];
    const float* W1     = (const float*)d_in[3];
    const float* b1     = (const float*)d_in[4];
    const float* W2     = (const float*)d_in[5];
    const float* b2     = (const float*)d_in[6];
    const float* W_ih   = (const float*)d_in[7];
    const float* W_hh   = (const float*)d_in[8];
    const float* b_ih   = (const float*)d_in[9];
    const float* b_hh   = (const float*)d_in[10];
    const float* Wp     = (const float*)d_in[11];
    const float* bp     = (const float*)d_in[12];
    float* out = (float*)d_out;

    float* seq = (float*)d_ws;                       // 8192*128
    float* xg  = seq + (size_t)GG * HH;              // 8192*384
    float* WT  = xg + (size_t)GG * 3 * RHH;          // 128*384

    transpose_wih<<<192, 256, 0, stream>>>(W_ih, WT);
    gcn_fused<<<GG, 256, 0, stream>>>(x, eidx, runner, W1, b1, W2, b2, seq);
    xg_kernel<<<GG / 8, 384, 0, stream>>>(seq, WT, b_ih, xg);
    gru_kernel<<<BBB, 768, 0, stream>>>(xg, W_hh, b_hh, Wp, bp, out);
}

// Round 2
// 264.887 us; speedup vs baseline: 1.1171x; 1.1171x over previous
//
#include <hip/hip_runtime.h>
#include <hip/hip_bf16.h>
#include <math.h>

#define GG 8192      // graphs = B*T
#define NODESN 23
#define KK 8
#define DIN 16
#define HH 128
#define RHH 128
#define EPG (NODESN*KK)   // 184 edges per graph
#define TTT 128
#define BBB 64
#define HPAD 132     // h_hist row stride: breaks bank conflicts, keeps 16B align

// ---------------------------------------------------------------------------
// Kernel 1: fully fused 2-layer GCN, one block per graph.
// deg == 9 for every node (deterministic dst pattern), so norm = 1/9.
// Only the runner node's layer-2 output is needed:
//   h2[runner] = relu( (1/9) * (hsum @ W2) + b2 ),  hsum = sum of 9 relu'd h1 rows
// ---------------------------------------------------------------------------
__global__ __launch_bounds__(256) void gcn_fused(
    const float* __restrict__ x, const int* __restrict__ esrc,
    const int* __restrict__ runner,
    const float* __restrict__ W1, const float* __restrict__ b1,
    const float* __restrict__ W2, const float* __restrict__ b2,
    float* __restrict__ seq)
{
    __shared__ float xs[NODESN * DIN];     // 23*16
    __shared__ float W1s[DIN * HH];        // 16*128
    __shared__ int   srcs[EPG];            // 184 local src indices
    __shared__ float t1[NODESN * HH];      // 23*128  (x @ W1)
    __shared__ float b1s[HH];
    __shared__ float hsum[HH];
    __shared__ float red[256];

    const int g = blockIdx.x;
    const int tid = threadIdx.x;

    // ---- stage inputs ----
    for (int i = tid; i < NODESN * DIN; i += 256) xs[i] = x[g * NODESN * DIN + i];
    for (int i = tid; i < DIN * HH; i += 256)     W1s[i] = W1[i];
    for (int i = tid; i < EPG; i += 256)          srcs[i] = esrc[g * EPG + i] - g * NODESN;
    if (tid < HH) b1s[tid] = b1[tid];
    __syncthreads();

    // ---- t1 = x @ W1  (23x16 @ 16x128) ----
    for (int idx = tid; idx < NODESN * HH; idx += 256) {
        int n = idx >> 7, j = idx & 127;
        float acc = 0.f;
        #pragma unroll
        for (int k = 0; k < DIN; k += 4) {
            float4 xv = *(const float4*)&xs[n * DIN + k];
            acc = fmaf(xv.x, W1s[(k+0)*HH + j],
                  fmaf(xv.y, W1s[(k+1)*HH + j],
                  fmaf(xv.z, W1s[(k+2)*HH + j],
                  fmaf(xv.w, W1s[(k+3)*HH + j], acc))));
        }
        t1[idx] = acc;
    }
    __syncthreads();

    // ---- hsum = sum over 9 slots (runner + its 8 srcs) of relu'd h1 rows ----
    const int r = runner[g];
    {
        const int j = tid & 127, sgrp = tid >> 7;   // 2 slot groups
        float part = 0.f;
        for (int slot = sgrp; slot < 9; slot += 2) {
            int node = (slot < 8) ? srcs[r * KK + slot] : r;
            float acc = t1[node * HH + j];
            #pragma unroll
            for (int k = 0; k < KK; k++) acc += t1[srcs[node * KK + k] * HH + j];
            part += fmaxf(acc * (1.f / 9.f) + b1s[j], 0.f);
        }
        red[tid] = part;
    }
    __syncthreads();
    if (tid < HH) hsum[tid] = red[tid] + red[tid + 128];
    __syncthreads();

    // ---- h2_runner = relu( (1/9)*(hsum @ W2) + b2 ) ; write to seq[g] ----
    {
        const int j = tid & 127, kh = tid >> 7;  // 2-way k split
        float acc = 0.f;
        #pragma unroll
        for (int kq = 0; kq < 16; kq++) {
            int k = kh * 64 + kq * 4;
            float4 hv = *(const float4*)&hsum[k];
            acc = fmaf(hv.x, W2[(k+0)*HH + j],
                  fmaf(hv.y, W2[(k+1)*HH + j],
                  fmaf(hv.z, W2[(k+2)*HH + j],
                  fmaf(hv.w, W2[(k+3)*HH + j], acc))));
        }
        red[tid] = acc;
    }
    __syncthreads();
    if (tid < HH)
        seq[(size_t)g * HH + tid] =
            fmaxf((red[tid] + red[tid + 128]) * (1.f / 9.f) + b2[tid], 0.f);
}

// ---------------------------------------------------------------------------
// Kernel 2: transpose W_ih [384,128] -> WT [128,384]
// ---------------------------------------------------------------------------
__global__ void transpose_wih(const float* __restrict__ W, float* __restrict__ WT)
{
    int idx = blockIdx.x * 256 + threadIdx.x;
    if (idx < 3 * RHH * RHH) {
        int jj = idx / RHH, kk = idx - jj * RHH;
        WT[kk * (3 * RHH) + jj] = W[idx];
    }
}

// ---------------------------------------------------------------------------
// Kernel 3: xg = seq @ W_ih^T + b_ih   [8192,128]@[128,384]
// ---------------------------------------------------------------------------
__global__ __launch_bounds__(384) void xg_kernel(
    const float* __restrict__ seq, const float* __restrict__ WT,
    const float* __restrict__ b_ih, float* __restrict__ xg)
{
    const int tid = threadIdx.x;              // j in [0,384)
    const int m0 = blockIdx.x * 8;
    const float* srow = seq + (size_t)m0 * RHH;
    float acc[8];
    const float bv = b_ih[tid];
    #pragma unroll
    for (int mi = 0; mi < 8; mi++) acc[mi] = bv;
    for (int k = 0; k < RHH; k += 4) {
        float w0 = WT[(k+0)*384 + tid];
        float w1 = WT[(k+1)*384 + tid];
        float w2 = WT[(k+2)*384 + tid];
        float w3 = WT[(k+3)*384 + tid];
        #pragma unroll
        for (int mi = 0; mi < 8; mi++) {
            float4 sv = *(const float4*)(srow + mi * RHH + k);
            acc[mi] = fmaf(sv.x, w0, fmaf(sv.y, w1, fmaf(sv.z, w2, fmaf(sv.w, w3, acc[mi]))));
        }
    }
    #pragma unroll
    for (int mi = 0; mi < 8; mi++)
        xg[(size_t)(m0 + mi) * 384 + tid] = acc[mi];
}

// ---------------------------------------------------------------------------
// Kernel 4: GRU + fused output projection. One block of 512 per batch element.
// Thread (i,q): i = hidden unit, q = k-quarter. 96 W_hh weights in VGPRs.
// Partial dots combine via __shfl_xor (q pairs = adjacent lanes) -> ONE
// __syncthreads per timestep (h_hist rows are write-once, no WAR hazard).
// xg rows double-buffered in LDS, prefetched one step ahead (coalesced).
// ---------------------------------------------------------------------------
__global__ __launch_bounds__(512) void gru_kernel(
    const float* __restrict__ xg, const float* __restrict__ W_hh,
    const float* __restrict__ b_hh, const float* __restrict__ Wp,
    const float* __restrict__ bp, float* __restrict__ out)
{
    __shared__ float h_hist[(TTT + 1) * HPAD];   // 129*132*4 = 68112 B
    __shared__ float xg_s[2][3 * RHH];           // 3072 B

    const int b   = blockIdx.x;
    const int tid = threadIdx.x;
    const int i   = tid >> 2;      // hidden index 0..127
    const int q   = tid & 3;       // k-quarter 0..3

    // ---- preload W_hh slices into VGPRs: rows i, 128+i, 256+i; cols [32q,32q+32)
    float wr[32], wz[32], wn[32];
    {
        const float* br = W_hh + (size_t)i * RHH + q * 32;
        const float* bz = br + (size_t)RHH * RHH;
        const float* bn = bz + (size_t)RHH * RHH;
        #pragma unroll
        for (int m = 0; m < 8; m++) {
            float4 v;
            v = *(const float4*)(br + 4*m); wr[4*m]=v.x; wr[4*m+1]=v.y; wr[4*m+2]=v.z; wr[4*m+3]=v.w;
            v = *(const float4*)(bz + 4*m); wz[4*m]=v.x; wz[4*m+1]=v.y; wz[4*m+2]=v.z; wz[4*m+3]=v.w;
            v = *(const float4*)(bn + 4*m); wn[4*m]=v.x; wn[4*m+1]=v.y; wn[4*m+2]=v.z; wn[4*m+3]=v.w;
        }
    }
    float bhr = 0.f, bhz = 0.f, bhn = 0.f;
    if (q == 0) { bhr = b_hh[i]; bhz = b_hh[RHH + i]; bhn = b_hh[2 * RHH + i]; }

    // ---- init: h0 = 0; prime xg double buffer
    if (tid < RHH) h_hist[tid] = 0.f;
    const float* xbase = xg + (size_t)b * TTT * 3 * RHH;
    float xnext = 0.f;
    if (tid < 3 * RHH) {
        xg_s[0][tid] = xbase[tid];             // t = 0
        xnext = xbase[3 * RHH + tid];          // t = 1
    }
    float hprev = 0.f;                          // this thread's own h[i] (q==0)
    __syncthreads();

    for (int t = 0; t < TTT; t++) {
        // partial dots over k-slice [32q, 32q+32)
        const float* hs = &h_hist[t * HPAD + q * 32];
        float ar = 0.f, az = 0.f, an = 0.f;
        #pragma unroll
        for (int m = 0; m < 8; m++) {
            float4 hv = *(const float4*)(hs + 4 * m);
            ar = fmaf(hv.x, wr[4*m], fmaf(hv.y, wr[4*m+1], fmaf(hv.z, wr[4*m+2], fmaf(hv.w, wr[4*m+3], ar))));
            az = fmaf(hv.x, wz[4*m], fmaf(hv.y, wz[4*m+1], fmaf(hv.z, wz[4*m+2], fmaf(hv.w, wz[4*m+3], az))));
            an = fmaf(hv.x, wn[4*m], fmaf(hv.y, wn[4*m+1], fmaf(hv.z, wn[4*m+2], fmaf(hv.w, wn[4*m+3], an))));
        }

        // publish next step's xg while dots are in flight
        if (tid < 3 * RHH) {
            xg_s[(t + 1) & 1][tid] = xnext;
            xnext = (t + 2 < TTT) ? xbase[(size_t)(t + 2) * 3 * RHH + tid] : 0.f;
        }

        // reduce across q (adjacent lanes)
        ar += __shfl_xor(ar, 1); ar += __shfl_xor(ar, 2);
        az += __shfl_xor(az, 1); az += __shfl_xor(az, 2);
        an += __shfl_xor(an, 1); an += __shfl_xor(an, 2);

        if (q == 0) {
            const float* xr_s = xg_s[t & 1];
            float xr = xr_s[i], xz = xr_s[RHH + i], xn = xr_s[2 * RHH + i];
            float sr = xr + ar + bhr;
            float sz = xz + az + bhz;
            float rg = 1.f / (1.f + __expf(-sr));
            float zg = 1.f / (1.f + __expf(-sz));
            float tv = fmaf(rg, an + bhn, xn);
            tv = fminf(fmaxf(tv, -15.f), 15.f);
            float e2 = __expf(-2.f * tv);
            float ng = (1.f - e2) / (1.f + e2);
            hprev = fmaf(zg, hprev, (1.f - zg) * ng);
            h_hist[(t + 1) * HPAD + i] = hprev;
        }
        __syncthreads();
    }

    // ---- stage Wp/bp, then fused projection out[b,t,:] = h_hist[t+1] @ Wp + bp
    if (tid < 2 * RHH) xg_s[0][tid] = Wp[tid];
    if (tid < 2)       xg_s[1][tid] = bp[tid];
    __syncthreads();

    for (int idx = tid; idx < TTT * 2; idx += 512) {
        int t = idx >> 1, c = idx & 1;
        float acc = xg_s[1][c];
        const float* hrow = &h_hist[(t + 1) * HPAD];
        #pragma unroll 4
        for (int ii = 0; ii < RHH; ii++)
            acc = fmaf(hrow[ii], xg_s[0][ii * 2 + c], acc);
        out[((size_t)b * TTT + t) * 2 + c] = acc;
    }
}

extern "C" void kernel_launch(void* const* d_in, const int* in_sizes, int n_in,
                              void* d_out, int out_size, void* d_ws, size_t ws_size,
                              hipStream_t stream)
{
    const float* x      = (const float*)d_in[0];
    const int*   eidx   = (const int*)d_in[1];   // [2, E]; row 0 = src
    const int*   runner = (const int*)d_in[2];
    const float* W1     = (const float*)d_in[3];
    const float* b1     = (const float*)d_in[4];
    const float* W2     = (const float*)d_in[5];
    const float* b2     = (const float*)d_in[6];
    const float* W_ih   = (const float*)d_in[7];
    const float* W_hh   = (const float*)d_in[8];
    const float* b_ih   = (const float*)d_in[9];
    const float* b_hh   = (const float*)d_in[10];
    const float* Wp     = (const float*)d_in[11];
    const float* bp     = (const float*)d_in[12];
    float* out = (float*)d_out;

    float* seq = (float*)d_ws;                       // 8192*128
    float* xg  = seq + (size_t)GG * HH;              // 8192*384
    float* WT  = xg + (size_t)GG * 3 * RHH;          // 128*384

    transpose_wih<<<192, 256, 0, stream>>>(W_ih, WT);
    gcn_fused<<<GG, 256, 0, stream>>>(x, eidx, runner, W1, b1, W2, b2, seq);
    xg_kernel<<<GG / 8, 384, 0, stream>>>(seq, WT, b_ih, xg);
    gru_kernel<<<BBB, 512, 0, stream>>>(xg, W_hh, b_hh, Wp, bp, out);
}

// Round 3
// 264.806 us; speedup vs baseline: 1.1175x; 1.0003x over previous
//
#include <hip/hip_runtime.h>
#include <hip/hip_bf16.h>
#include <math.h>

#define GG 8192      // graphs = B*T
#define NODESN 23
#define KK 8
#define DIN 16
#define HH 128
#define RHH 128
#define EPG (NODESN*KK)   // 184 edges per graph
#define TTT 128
#define BBB 64
#define HPAD 132     // h_hist row stride: 16B-aligned, breaks cross-row patterns

// barrier with LDS-only drain: leaves global prefetch loads in flight
#define GRU_BARRIER() asm volatile("s_waitcnt lgkmcnt(0)\n\ts_barrier" ::: "memory")

// ---------------------------------------------------------------------------
// Kernel 1: fully fused 2-layer GCN, one block per graph.
// deg == 9 for every node (deterministic dst pattern), so norm = 1/9.
// Only the runner node's layer-2 output is needed.
// ---------------------------------------------------------------------------
__global__ __launch_bounds__(256) void gcn_fused(
    const float* __restrict__ x, const int* __restrict__ esrc,
    const int* __restrict__ runner,
    const float* __restrict__ W1, const float* __restrict__ b1,
    const float* __restrict__ W2, const float* __restrict__ b2,
    float* __restrict__ seq)
{
    __shared__ float xs[NODESN * DIN];
    __shared__ float W1s[DIN * HH];
    __shared__ int   srcs[EPG];
    __shared__ float t1[NODESN * HH];
    __shared__ float b1s[HH];
    __shared__ float hsum[HH];
    __shared__ float red[256];

    const int g = blockIdx.x;
    const int tid = threadIdx.x;

    for (int i = tid; i < NODESN * DIN; i += 256) xs[i] = x[g * NODESN * DIN + i];
    for (int i = tid; i < DIN * HH; i += 256)     W1s[i] = W1[i];
    for (int i = tid; i < EPG; i += 256)          srcs[i] = esrc[g * EPG + i] - g * NODESN;
    if (tid < HH) b1s[tid] = b1[tid];
    __syncthreads();

    for (int idx = tid; idx < NODESN * HH; idx += 256) {
        int n = idx >> 7, j = idx & 127;
        float acc = 0.f;
        #pragma unroll
        for (int k = 0; k < DIN; k += 4) {
            float4 xv = *(const float4*)&xs[n * DIN + k];
            acc = fmaf(xv.x, W1s[(k+0)*HH + j],
                  fmaf(xv.y, W1s[(k+1)*HH + j],
                  fmaf(xv.z, W1s[(k+2)*HH + j],
                  fmaf(xv.w, W1s[(k+3)*HH + j], acc))));
        }
        t1[idx] = acc;
    }
    __syncthreads();

    const int r = runner[g];
    {
        const int j = tid & 127, sgrp = tid >> 7;
        float part = 0.f;
        for (int slot = sgrp; slot < 9; slot += 2) {
            int node = (slot < 8) ? srcs[r * KK + slot] : r;
            float acc = t1[node * HH + j];
            #pragma unroll
            for (int k = 0; k < KK; k++) acc += t1[srcs[node * KK + k] * HH + j];
            part += fmaxf(acc * (1.f / 9.f) + b1s[j], 0.f);
        }
        red[tid] = part;
    }
    __syncthreads();
    if (tid < HH) hsum[tid] = red[tid] + red[tid + 128];
    __syncthreads();

    {
        const int j = tid & 127, kh = tid >> 7;
        float acc = 0.f;
        #pragma unroll
        for (int kq = 0; kq < 16; kq++) {
            int k = kh * 64 + kq * 4;
            float4 hv = *(const float4*)&hsum[k];
            acc = fmaf(hv.x, W2[(k+0)*HH + j],
                  fmaf(hv.y, W2[(k+1)*HH + j],
                  fmaf(hv.z, W2[(k+2)*HH + j],
                  fmaf(hv.w, W2[(k+3)*HH + j], acc))));
        }
        red[tid] = acc;
    }
    __syncthreads();
    if (tid < HH)
        seq[(size_t)g * HH + tid] =
            fmaxf((red[tid] + red[tid + 128]) * (1.f / 9.f) + b2[tid], 0.f);
}

// ---------------------------------------------------------------------------
// Kernel 2: transpose W_ih [384,128] -> WT [128,384]
// ---------------------------------------------------------------------------
__global__ void transpose_wih(const float* __restrict__ W, float* __restrict__ WT)
{
    int idx = blockIdx.x * 256 + threadIdx.x;
    if (idx < 3 * RHH * RHH) {
        int jj = idx / RHH, kk = idx - jj * RHH;
        WT[kk * (3 * RHH) + jj] = W[idx];
    }
}

// ---------------------------------------------------------------------------
// Kernel 3: xg = seq @ W_ih^T + b_ih   [8192,128]@[128,384]
// ---------------------------------------------------------------------------
__global__ __launch_bounds__(384) void xg_kernel(
    const float* __restrict__ seq, const float* __restrict__ WT,
    const float* __restrict__ b_ih, float* __restrict__ xg)
{
    const int tid = threadIdx.x;
    const int m0 = blockIdx.x * 8;
    const float* srow = seq + (size_t)m0 * RHH;
    float acc[8];
    const float bv = b_ih[tid];
    #pragma unroll
    for (int mi = 0; mi < 8; mi++) acc[mi] = bv;
    for (int k = 0; k < RHH; k += 4) {
        float w0 = WT[(k+0)*384 + tid];
        float w1 = WT[(k+1)*384 + tid];
        float w2 = WT[(k+2)*384 + tid];
        float w3 = WT[(k+3)*384 + tid];
        #pragma unroll
        for (int mi = 0; mi < 8; mi++) {
            float4 sv = *(const float4*)(srow + mi * RHH + k);
            acc[mi] = fmaf(sv.x, w0, fmaf(sv.y, w1, fmaf(sv.z, w2, fmaf(sv.w, w3, acc[mi]))));
        }
    }
    #pragma unroll
    for (int mi = 0; mi < 8; mi++)
        xg[(size_t)(m0 + mi) * 384 + tid] = acc[mi];
}

// ---------------------------------------------------------------------------
// Kernel 4: GRU + fused output projection. One block of 512 per batch element.
// Thread (i,q): i = hidden unit, q = k-quarter; 96 W_hh weights in VGPRs
// (__launch_bounds__(512,2) raises the VGPR cap so they actually stay there).
// q-slices traverse k in rotated phase order -> disjoint LDS bank groups.
// One LDS-only barrier per step (asm: s_waitcnt lgkmcnt(0); s_barrier) so the
// xg global prefetch is never drained by the barrier.
// ---------------------------------------------------------------------------
__global__ __launch_bounds__(512, 2) void gru_kernel(
    const float* __restrict__ xg, const float* __restrict__ W_hh,
    const float* __restrict__ b_hh, const float* __restrict__ Wp,
    const float* __restrict__ bp, float* __restrict__ out)
{
    __shared__ float h_hist[(TTT + 1) * HPAD];   // 129*132*4 = 68112 B
    __shared__ float xg_s[2][3 * RHH];           // 3072 B

    const int b   = blockIdx.x;
    const int tid = threadIdx.x;
    const int i   = tid >> 2;      // hidden index 0..127
    const int q   = tid & 3;       // k-quarter 0..3

    // ---- preload W_hh slices into VGPRs, in phase-rotated order:
    // register group m holds cols q*32 + 4*((m+2q)&7) .. +3
    float wr[32], wz[32], wn[32];
    int loff[8];                   // per-m LDS float-offset within an h row
    {
        const float* br = W_hh + (size_t)i * RHH + q * 32;
        const float* bz = br + (size_t)RHH * RHH;
        const float* bn = bz + (size_t)RHH * RHH;
        #pragma unroll
        for (int m = 0; m < 8; m++) {
            int p = (m + 2 * q) & 7;
            loff[m] = q * 32 + 4 * p;
            float4 v;
            v = *(const float4*)(br + 4*p); wr[4*m]=v.x; wr[4*m+1]=v.y; wr[4*m+2]=v.z; wr[4*m+3]=v.w;
            v = *(const float4*)(bz + 4*p); wz[4*m]=v.x; wz[4*m+1]=v.y; wz[4*m+2]=v.z; wz[4*m+3]=v.w;
            v = *(const float4*)(bn + 4*p); wn[4*m]=v.x; wn[4*m+1]=v.y; wn[4*m+2]=v.z; wn[4*m+3]=v.w;
        }
    }
    float bhr = 0.f, bhz = 0.f, bhn = 0.f;
    if (q == 0) { bhr = b_hh[i]; bhz = b_hh[RHH + i]; bhn = b_hh[2 * RHH + i]; }

    if (tid < RHH) h_hist[tid] = 0.f;
    const float* xbase = xg + (size_t)b * TTT * 3 * RHH;
    float xnext = 0.f;
    if (tid < 3 * RHH) {
        xg_s[0][tid] = xbase[tid];             // t = 0
        xnext = xbase[3 * RHH + tid];          // t = 1
    }
    float hprev = 0.f;
    __syncthreads();

    for (int t = 0; t < TTT; t++) {
        const float* hrow = &h_hist[t * HPAD];
        float ar0 = 0.f, ar1 = 0.f, az0 = 0.f, az1 = 0.f, an0 = 0.f, an1 = 0.f;
        #pragma unroll
        for (int m = 0; m < 8; m++) {
            float4 hv = *(const float4*)(hrow + loff[m]);
            if (m & 1) {
                ar1 = fmaf(hv.x, wr[4*m], fmaf(hv.y, wr[4*m+1], fmaf(hv.z, wr[4*m+2], fmaf(hv.w, wr[4*m+3], ar1))));
                az1 = fmaf(hv.x, wz[4*m], fmaf(hv.y, wz[4*m+1], fmaf(hv.z, wz[4*m+2], fmaf(hv.w, wz[4*m+3], az1))));
                an1 = fmaf(hv.x, wn[4*m], fmaf(hv.y, wn[4*m+1], fmaf(hv.z, wn[4*m+2], fmaf(hv.w, wn[4*m+3], an1))));
            } else {
                ar0 = fmaf(hv.x, wr[4*m], fmaf(hv.y, wr[4*m+1], fmaf(hv.z, wr[4*m+2], fmaf(hv.w, wr[4*m+3], ar0))));
                az0 = fmaf(hv.x, wz[4*m], fmaf(hv.y, wz[4*m+1], fmaf(hv.z, wz[4*m+2], fmaf(hv.w, wz[4*m+3], az0))));
                an0 = fmaf(hv.x, wn[4*m], fmaf(hv.y, wn[4*m+1], fmaf(hv.z, wn[4*m+2], fmaf(hv.w, wn[4*m+3], an0))));
            }
        }
        float ar = ar0 + ar1, az = az0 + az1, an = an0 + an1;

        // publish next step's xg while dots are in flight
        if (tid < 3 * RHH) {
            xg_s[(t + 1) & 1][tid] = xnext;
            xnext = (t + 2 < TTT) ? xbase[(size_t)(t + 2) * 3 * RHH + tid] : 0.f;
        }

        // reduce across q (adjacent lanes -> DPP quad_perm)
        ar += __shfl_xor(ar, 1); ar += __shfl_xor(ar, 2);
        az += __shfl_xor(az, 1); az += __shfl_xor(az, 2);
        an += __shfl_xor(an, 1); an += __shfl_xor(an, 2);

        if (q == 0) {
            const float* xr_s = xg_s[t & 1];
            float xr = xr_s[i], xz = xr_s[RHH + i], xn = xr_s[2 * RHH + i];
            float sr = xr + ar + bhr;
            float sz = xz + az + bhz;
            float rg = 1.f / (1.f + __expf(-sr));
            float zg = 1.f / (1.f + __expf(-sz));
            float tv = fmaf(rg, an + bhn, xn);
            tv = fminf(fmaxf(tv, -15.f), 15.f);
            float e2 = __expf(-2.f * tv);
            float ng = (1.f - e2) / (1.f + e2);
            hprev = fmaf(zg, hprev, (1.f - zg) * ng);
            h_hist[(t + 1) * HPAD + i] = hprev;
        }
        GRU_BARRIER();
    }

    // ---- stage Wp/bp, fused projection out[b,t,:] = h_hist[t+1] @ Wp + bp
    if (tid < 2 * RHH) xg_s[0][tid] = Wp[tid];
    if (tid < 2)       xg_s[1][tid] = bp[tid];
    __syncthreads();

    // thread -> (t, c, s): s = k-quarter of the 128-dot, reduced via shfl
    #pragma unroll
    for (int pass = 0; pass < 2; pass++) {
        int t = (tid >> 3) + pass * 64;
        int c = (tid >> 2) & 1;
        int s = tid & 3;  // wait—need s in low bits for shfl; recompute below
        (void)s;
        // layout: low 2 bits = s (shfl distance 1,2), bit2 = c, bits3+ = t
        int s2 = tid & 3;
        float acc = 0.f;
        const float* hr = &h_hist[(t + 1) * HPAD + s2 * 32];
        #pragma unroll
        for (int ii = 0; ii < 32; ii += 4) {
            float4 hv = *(const float4*)(hr + ii);
            int k = s2 * 32 + ii;
            acc = fmaf(hv.x, xg_s[0][(k+0)*2 + c],
                  fmaf(hv.y, xg_s[0][(k+1)*2 + c],
                  fmaf(hv.z, xg_s[0][(k+2)*2 + c],
                  fmaf(hv.w, xg_s[0][(k+3)*2 + c], acc))));
        }
        acc += __shfl_xor(acc, 1);
        acc += __shfl_xor(acc, 2);
        if (s2 == 0)
            out[((size_t)b * TTT + t) * 2 + c] = acc + xg_s[1][c];
    }
}

extern "C" void kernel_launch(void* const* d_in, const int* in_sizes, int n_in,
                              void* d_out, int out_size, void* d_ws, size_t ws_size,
                              hipStream_t stream)
{
    const float* x      = (const float*)d_in[0];
    const int*   eidx   = (const int*)d_in[1];
    const int*   runner = (const int*)d_in[2];
    const float* W1     = (const float*)d_in[3];
    const float* b1     = (const float*)d_in[4];
    const float* W2     = (const float*)d_in[5];
    const float* b2     = (const float*)d_in[6];
    const float* W_ih   = (const float*)d_in[7];
    const float* W_hh   = (const float*)d_in[8];
    const float* b_ih   = (const float*)d_in[9];
    const float* b_hh   = (const float*)d_in[10];
    const float* Wp     = (const float*)d_in[11];
    const float* bp     = (const float*)d_in[12];
    float* out = (float*)d_out;

    float* seq = (float*)d_ws;                       // 8192*128
    float* xg  = seq + (size_t)GG * HH;              // 8192*384
    float* WT  = xg + (size_t)GG * 3 * RHH;          // 128*384

    transpose_wih<<<192, 256, 0, stream>>>(W_ih, WT);
    gcn_fused<<<GG, 256, 0, stream>>>(x, eidx, runner, W1, b1, W2, b2, seq);
    xg_kernel<<<GG / 8, 384, 0, stream>>>(seq, WT, b_ih, xg);
    gru_kernel<<<BBB, 512, 0, stream>>>(xg, W_hh, b_hh, Wp, bp, out);
}